// Round 1
// baseline (140.940 us; speedup 1.0000x reference)
//
#include <hip/hip_runtime.h>

// GAT-style graph conv: B=2, C=128, N=10000, K=16, fp32.
// Decomposition:
//   k1: wht[b][n][c] = sum_ci W[c][ci] * x[b][ci][n]   (node-major for gathers)
//       si[b][n] = a[0:C]   . wht[b][n][:]
//       sj[b][n] = a[C:2C]  . wht[b][n][:]
//   k2: e[n,k] = leaky(si[idx_i] + sj[idx_j]); A = softmax_k(e)
//       out[b][c][n] = sum_k A[n,k] * wht[b][idx_j[n,k]][c]

#define BB 2
#define CC 128
#define NN 10000
#define KK 16
#define TN 32   // nodes per block

__global__ __launch_bounds__(256) void gat_gemm(
    const float* __restrict__ x,    // [B,C,N]
    const float* __restrict__ W,    // [C,C] row-major: W[o][c]
    const float* __restrict__ a,    // [2C]
    float* __restrict__ wht,        // [B,N,C]
    float* __restrict__ si,         // [B,N]
    float* __restrict__ sj) {       // [B,N]
  __shared__ float xs[CC][TN];       // 16 KB: x tile, [c_in][n]
  __shared__ float wt[TN][CC + 1];   // 16.5 KB: output tile, padded (129%32=1 -> 2-way only)
  __shared__ float redi[8][TN];
  __shared__ float redj[8][TN];

  const int b  = blockIdx.y;
  const int n0 = blockIdx.x * TN;
  const int t  = threadIdx.x;
  const float* xb = x + b * CC * NN;

  // Stage x tile: consecutive lanes -> consecutive nodes (coalesced global reads).
#pragma unroll
  for (int i = 0; i < (CC * TN) / 256; ++i) {   // 16 iters
    int e = t + i * 256;
    int c = e >> 5, n = e & 31;
    int gn = n0 + n;
    xs[c][n] = (gn < NN) ? xb[c * NN + gn] : 0.f;
  }
  __syncthreads();

  // Thread owns node n = t%32 and 16 output channels co..co+15.
  const int n   = t & 31;
  const int sub = t >> 5;      // 0..7
  const int co  = sub * 16;

  float acc[16];
#pragma unroll
  for (int j = 0; j < 16; ++j) acc[j] = 0.f;

  // W rows read contiguously (float4 x2 per row-chunk); only 2 unique
  // addresses per wave-instr (2 subs/wave), L1/L2-resident (64 KB total).
  for (int c0 = 0; c0 < CC; c0 += 8) {
    float xv[8];
#pragma unroll
    for (int u = 0; u < 8; ++u) xv[u] = xs[c0 + u][n];   // broadcast pairs, conflict-free
#pragma unroll
    for (int j = 0; j < 16; ++j) {
      const float4* wp = (const float4*)(W + (co + j) * CC + c0);
      float4 w0 = wp[0];
      float4 w1 = wp[1];
      acc[j] = fmaf(w0.x, xv[0], acc[j]);
      acc[j] = fmaf(w0.y, xv[1], acc[j]);
      acc[j] = fmaf(w0.z, xv[2], acc[j]);
      acc[j] = fmaf(w0.w, xv[3], acc[j]);
      acc[j] = fmaf(w1.x, xv[4], acc[j]);
      acc[j] = fmaf(w1.y, xv[5], acc[j]);
      acc[j] = fmaf(w1.z, xv[6], acc[j]);
      acc[j] = fmaf(w1.w, xv[7], acc[j]);
    }
  }

  // Stash tile + partial a-dots.
  float psi = 0.f, psj = 0.f;
#pragma unroll
  for (int j = 0; j < 16; ++j) {
    wt[n][co + j] = acc[j];
    psi = fmaf(a[co + j], acc[j], psi);
    psj = fmaf(a[CC + co + j], acc[j], psj);
  }
  redi[sub][n] = psi;
  redj[sub][n] = psj;
  __syncthreads();

  // Coalesced node-major store: consecutive lanes -> consecutive channels.
  float* wb = wht + (b * NN + n0) * CC;
#pragma unroll
  for (int i = 0; i < (CC * TN) / 256; ++i) {   // 16 iters
    int e = t + i * 256;
    int nn = e >> 7, c = e & 127;
    int gn = n0 + nn;
    if (gn < NN) wb[nn * CC + c] = wt[nn][c];
  }

  // Reduce si/sj across the 8 sub-threads per node.
  if (t < TN) {
    int gn = n0 + t;
    if (gn < NN) {
      float s1 = 0.f, s2 = 0.f;
#pragma unroll
      for (int s = 0; s < 8; ++s) { s1 += redi[s][t]; s2 += redj[s][t]; }
      si[b * NN + gn] = s1;
      sj[b * NN + gn] = s2;
    }
  }
}

__global__ __launch_bounds__(256) void gat_gather(
    const int* __restrict__ ei,     // [2,B,N,K]
    const float* __restrict__ wht,  // [B,N,C]
    const float* __restrict__ si,   // [B,N]
    const float* __restrict__ sj,   // [B,N]
    float* __restrict__ out) {      // [B,C,N]
  __shared__ float Am[TN][KK + 1];     // attention weights, padded
  __shared__ int   jd[TN][KK];         // idx_j per edge
  __shared__ float outT[CC][TN + 1];   // 16.9 KB staged output tile [c][n]

  const int b  = blockIdx.y;
  const int n0 = blockIdx.x * TN;
  const int t  = threadIdx.x;

  const int* eij = ei + b * NN * KK;        // edge_index[0][b] -> j (source)
  const int* eii = ei + (2 + b) * NN * KK;  // edge_index[1][b] -> i (dest)
  const float* sib = si + b * NN;
  const float* sjb = sj + b * NN;

  // Phase A: logits per edge (scalar gathers of si/sj, L2-resident).
#pragma unroll
  for (int i = 0; i < (TN * KK) / 256; ++i) {   // 2 iters
    int e = t + i * 256;
    int nn = e >> 4, k = e & 15;
    int gn = n0 + nn;
    float el = 0.f;
    int jj = 0;
    if (gn < NN) {
      jj = eij[gn * KK + k];
      int ii = eii[gn * KK + k];
      float v = sib[ii] + sjb[jj];
      el = (v > 0.f) ? v : 0.2f * v;   // leaky_relu(0.2)
    }
    Am[nn][k] = el;
    jd[nn][k] = jj;
  }
  __syncthreads();

  // Phase B: softmax over K=16 per node (one thread per node).
  if (t < TN) {
    float mx = Am[t][0];
#pragma unroll
    for (int k = 1; k < KK; ++k) mx = fmaxf(mx, Am[t][k]);
    float s = 0.f, ex[KK];
#pragma unroll
    for (int k = 0; k < KK; ++k) { ex[k] = __expf(Am[t][k] - mx); s += ex[k]; }
    float inv = 1.f / s;
#pragma unroll
    for (int k = 0; k < KK; ++k) Am[t][k] = ex[k] * inv;
  }
  __syncthreads();

  // Phase C: weighted aggregation. One wave per node; lane l owns channels
  // 2l,2l+1 -> each gather is one coalesced 512 B float2-per-lane row read.
  const int wv = t >> 6, lane = t & 63;
  const float* whtb = wht + b * NN * CC;
  for (int nn = wv; nn < TN; nn += 4) {   // 8 nodes per wave
    int gn = n0 + nn;
    if (gn < NN) {
      float ax = 0.f, ay = 0.f;
#pragma unroll
      for (int k = 0; k < KK; ++k) {
        int m   = jd[nn][k];     // wave-uniform LDS read (broadcast)
        float w = Am[nn][k];
        const float2* p = (const float2*)(whtb + m * CC) + lane;
        float2 v = *p;
        ax = fmaf(w, v.x, ax);
        ay = fmaf(w, v.y, ay);
      }
      outT[2 * lane][nn]     = ax;
      outT[2 * lane + 1][nn] = ay;
    }
  }
  __syncthreads();

  // Coalesced channel-major store: consecutive lanes -> consecutive nodes.
  float* outb = out + b * CC * NN;
#pragma unroll
  for (int i = 0; i < (CC * TN) / 256; ++i) {   // 16 iters
    int e = t + i * 256;
    int c = e >> 5, nn = e & 31;
    int gn = n0 + nn;
    if (gn < NN) outb[c * NN + gn] = outT[c][nn];
  }
}

extern "C" void kernel_launch(void* const* d_in, const int* in_sizes, int n_in,
                              void* d_out, int out_size, void* d_ws, size_t ws_size,
                              hipStream_t stream) {
  const float* x = (const float*)d_in[0];   // [B,C,N,1]
  const int*   ei = (const int*)d_in[1];    // [2,B,N,K]
  const float* W = (const float*)d_in[2];   // [C,C]
  const float* a = (const float*)d_in[3];   // [2C]
  float* out = (float*)d_out;               // [B,C,N,1]

  // Workspace: wht [B*N*C] + si [B*N] + sj [B*N]  (~10.4 MB)
  float* wht = (float*)d_ws;
  float* si  = wht + BB * NN * CC;
  float* sj  = si + BB * NN;

  dim3 grid((NN + TN - 1) / TN, BB);   // 313 x 2
  gat_gemm<<<grid, 256, 0, stream>>>(x, W, a, wht, si, sj);
  gat_gather<<<grid, 256, 0, stream>>>(ei, wht, si, sj, out);
}

// Round 2
// 113.553 us; speedup vs baseline: 1.2412x; 1.2412x over previous
//
#include <hip/hip_runtime.h>

// GAT-style graph conv: B=2, C=128, N=10000, K=16, fp32.
//   k1: wht[b][n][c] = sum_ci W[c][ci] * x[b][ci][n]   (node-major for gathers)
//       si[b][n] = a[0:C] . wht[b][n][:],  sj[b][n] = a[C:2C] . wht[b][n][:]
//   k2: e[n,k] = leaky(si[idx_i] + sj[idx_j]); A = softmax_k(e)
//       out[b][c][n] = sum_k A[n,k] * wht[b][idx_j[n,k]][c]

#define BB 2
#define CC 128
#define NN 10000
#define KK 16
#define TNG 32   // nodes per block (gemm)
#define TNA 16   // nodes per block (gather)

// ---------------- GEMM: W staged in LDS (broadcast reads), 80 KB -> 2 blocks/CU
__global__ __launch_bounds__(256, 2) void gat_gemm(
    const float* __restrict__ x,    // [B,C,N]
    const float* __restrict__ W,    // [C,C] row-major W[o][c]
    const float* __restrict__ a,    // [2C]
    float* __restrict__ wht,        // [B,N,C]
    float* __restrict__ si,         // [B,N]
    float* __restrict__ sj) {       // [B,N]
  __shared__ float lds[16384 + 4096];   // 80 KB exactly: W(64K) + xs(16K)
  float* Ws = lds;                      // [128][128]
  float* xs = lds + 16384;              // [128][TNG]  xs[c][n]

  const int b  = blockIdx.y;
  const int n0 = blockIdx.x * TNG;
  const int t  = threadIdx.x;

  // Stage W: 4096 float4 / 256 threads = 16 each, fully coalesced, L2-served.
  {
    const float4* Wg = (const float4*)W;
    float4* Wl = (float4*)Ws;
#pragma unroll
    for (int i = 0; i < 16; ++i) Wl[t + i * 256] = Wg[t + i * 256];
  }
  // Stage x tile: consecutive lanes -> consecutive nodes.
  const float* xb = x + b * CC * NN;
#pragma unroll
  for (int i = 0; i < 16; ++i) {
    int e = t + i * 256;
    int c = e >> 5, n = e & 31;
    int gn = n0 + n;
    xs[c * TNG + n] = (gn < NN) ? xb[c * NN + gn] : 0.f;
  }
  __syncthreads();

  // Thread owns node n = t%32, output channels co..co+15.
  const int n   = t & 31;
  const int sub = t >> 5;
  const int co  = sub * 16;

  float acc[16];
#pragma unroll
  for (int j = 0; j < 16; ++j) acc[j] = 0.f;

  for (int c0 = 0; c0 < CC; c0 += 8) {
    float xv[8];
#pragma unroll
    for (int u = 0; u < 8; ++u) xv[u] = xs[(c0 + u) * TNG + n];  // per-lane banks, free
#pragma unroll
    for (int j = 0; j < 16; ++j) {
      // Wave-broadcast LDS reads: 2 distinct addresses/wave (one per sub),
      // 2-way same-bank alias = free (m136).
      const float4* wp = (const float4*)(Ws + (co + j) * CC + c0);
      float4 w0 = wp[0];
      float4 w1 = wp[1];
      acc[j] = fmaf(w0.x, xv[0], acc[j]);
      acc[j] = fmaf(w0.y, xv[1], acc[j]);
      acc[j] = fmaf(w0.z, xv[2], acc[j]);
      acc[j] = fmaf(w0.w, xv[3], acc[j]);
      acc[j] = fmaf(w1.x, xv[4], acc[j]);
      acc[j] = fmaf(w1.y, xv[5], acc[j]);
      acc[j] = fmaf(w1.z, xv[6], acc[j]);
      acc[j] = fmaf(w1.w, xv[7], acc[j]);
    }
  }

  // Direct register->global store of wht row segment (64 B/thread, L2 merges).
  const int gn = n0 + n;
  if (gn < NN) {
    float4* wb = (float4*)(wht + ((size_t)(b * NN + gn)) * CC + co);
#pragma unroll
    for (int j = 0; j < 4; ++j)
      wb[j] = make_float4(acc[4 * j], acc[4 * j + 1], acc[4 * j + 2], acc[4 * j + 3]);
  }

  // a-dots (a is 1 KB, L1-resident).
  float psi = 0.f, psj = 0.f;
#pragma unroll
  for (int j = 0; j < 16; ++j) {
    psi = fmaf(a[co + j], acc[j], psi);
    psj = fmaf(a[CC + co + j], acc[j], psj);
  }

  // Reduce si/sj across the 8 subs per node; reuse xs region as scratch.
  __syncthreads();                 // everyone done reading xs
  float* red = xs;                 // [0..255]=psi, [256..511]=psj
  red[sub * 32 + n] = psi;
  red[256 + sub * 32 + n] = psj;
  __syncthreads();
  if (t < TNG) {
    int g = n0 + t;
    if (g < NN) {
      float s1 = 0.f, s2 = 0.f;
#pragma unroll
      for (int s = 0; s < 8; ++s) { s1 += red[s * 32 + t]; s2 += red[256 + s * 32 + t]; }
      si[b * NN + g] = s1;
      sj[b * NN + g] = s2;
    }
  }
}

// ---------------- Gather: 16 independent row-gathers in flight per thread
__global__ __launch_bounds__(256) void gat_gather(
    const int* __restrict__ ei,     // [2,B,N,K]
    const float* __restrict__ wht,  // [B,N,C]
    const float* __restrict__ si,   // [B,N]
    const float* __restrict__ sj,   // [B,N]
    float* __restrict__ out) {      // [B,C,N]
  __shared__ float Am[TNA][KK];        // 1 KB
  __shared__ int   jd[TNA][KK];        // 1 KB
  __shared__ float outT[CC][TNA + 1];  // 8.5 KB staged output tile [c][n]

  const int b  = blockIdx.y;
  const int n0 = blockIdx.x * TNA;
  const int t  = threadIdx.x;

  const int* eij = ei + b * NN * KK;            // edge_index[0][b] -> j
  const int* eii = ei + (BB + b) * NN * KK;     // edge_index[1][b] -> i
  const float* sib = si + b * NN;
  const float* sjb = sj + b * NN;

  // Phase A: one edge per thread (256 edges = TNA*KK).
  {
    int nn = t >> 4, k = t & 15, gn = n0 + nn;
    float el = 0.f; int jj = 0;
    if (gn < NN) {
      jj = eij[gn * KK + k];
      int ii = eii[gn * KK + k];
      float v = sib[ii] + sjb[jj];
      el = (v > 0.f) ? v : 0.2f * v;   // leaky_relu(0.2)
    }
    Am[nn][k] = el;
    jd[nn][k] = jj;
  }
  __syncthreads();

  // Phase B: softmax over K=16 per node.
  if (t < TNA) {
    float mx = Am[t][0];
#pragma unroll
    for (int k = 1; k < KK; ++k) mx = fmaxf(mx, Am[t][k]);
    float s = 0.f, ex[KK];
#pragma unroll
    for (int k = 0; k < KK; ++k) { ex[k] = __expf(Am[t][k] - mx); s += ex[k]; }
    float inv = 1.f / s;
#pragma unroll
    for (int k = 0; k < KK; ++k) Am[t][k] = ex[k] * inv;
  }
  __syncthreads();

  // Phase C: thread = (node nn, channel-pair cp). All 16 k-gathers are
  // independent float2 loads issued back-to-back (one vmcnt drain per node).
  const int cp = t & 63;      // wave = one node row, 64 lanes x 8 B = 512 B
  const int nw = t >> 6;      // 4 nodes in parallel per block pass
  const float* whtb = wht + (size_t)b * NN * CC;
  for (int nn = nw; nn < TNA; nn += 4) {
    int gn = n0 + nn;
    float ax = 0.f, ay = 0.f;
    if (gn < NN) {
      int   idx[KK];
      float wk[KK];
#pragma unroll
      for (int k = 0; k < KK; ++k) { idx[k] = jd[nn][k]; wk[k] = Am[nn][k]; }  // broadcast
      float2 v[KK];
#pragma unroll
      for (int k = 0; k < KK; ++k)
        v[k] = *((const float2*)(whtb + (size_t)idx[k] * CC) + cp);
#pragma unroll
      for (int k = 0; k < KK; ++k) {
        ax = fmaf(wk[k], v[k].x, ax);
        ay = fmaf(wk[k], v[k].y, ay);
      }
    }
    outT[2 * cp][nn]     = ax;
    outT[2 * cp + 1][nn] = ay;
  }
  __syncthreads();

  // Phase D: coalesced channel-major store.
  float* outb = out + (size_t)b * CC * NN;
#pragma unroll
  for (int i = 0; i < (CC * TNA) / 256; ++i) {   // 8 iters
    int e = t + i * 256;
    int c = e >> 4, nn = e & 15;
    int gn = n0 + nn;
    if (gn < NN) outb[c * NN + gn] = outT[c][nn];
  }
}

extern "C" void kernel_launch(void* const* d_in, const int* in_sizes, int n_in,
                              void* d_out, int out_size, void* d_ws, size_t ws_size,
                              hipStream_t stream) {
  const float* x = (const float*)d_in[0];   // [B,C,N,1]
  const int*   ei = (const int*)d_in[1];    // [2,B,N,K]
  const float* W = (const float*)d_in[2];   // [C,C]
  const float* a = (const float*)d_in[3];   // [2C]
  float* out = (float*)d_out;               // [B,C,N,1]

  float* wht = (float*)d_ws;                // [B*N*C]
  float* si  = wht + BB * NN * CC;          // [B*N]
  float* sj  = si + BB * NN;                // [B*N]

  dim3 g1((NN + TNG - 1) / TNG, BB);   // 313 x 2
  dim3 g2((NN + TNA - 1) / TNA, BB);   // 625 x 2
  gat_gemm<<<g1, 256, 0, stream>>>(x, W, a, wht, si, sj);
  gat_gather<<<g2, 256, 0, stream>>>(ei, wht, si, sj, out);
}

// Round 3
// 105.666 us; speedup vs baseline: 1.3338x; 1.0746x over previous
//
#include <hip/hip_runtime.h>

// GAT-style graph conv: B=2, C=128, N=10000, K=16, fp32 in/out.
//   k1 (gemm):  wht[b][n][c] = sum_ci W[c][ci]*x[b][ci][n]  (stored bf16, node-major)
//               si[b][n] = a[0:C].wh[n],  sj[b][n] = a[C:2C].wh[n]   (fp32)
//   k2 (gather): e = leaky(si[idx_i]+sj[idx_j]); A = softmax_k(e)
//               out[b][c][n] = sum_k A[n,k] * wht[b][idx_j[n,k]][c]
// Key structure: W reads are wave-uniform -> scalar s_load (readfirstlane trick);
// wht bf16 (2.56 MB/batch) is per-XCD-L2-resident for the random gathers.

#define BB 2
#define CC 128
#define NN 10000
#define KK 16
#define TNG 64   // nodes per block (gemm); wave = 64 nodes x 16 channels
#define TNA 16   // nodes per block (gather)

typedef unsigned int uint32;

__device__ __forceinline__ uint32 bf16pair(float lo, float hi) {
  // round-to-nearest-even bf16, packed (lo in low 16, hi in high 16)
  uint32 ulo = __float_as_uint(lo);
  uint32 uhi = __float_as_uint(hi);
  ulo += 0x7fffu + ((ulo >> 16) & 1u);
  uhi += 0x7fffu + ((uhi >> 16) & 1u);
  return (ulo >> 16) | (uhi & 0xffff0000u);
}

// ---------------- GEMM: scalar-pipe W, VALU does only FMA ----------------
__global__ __launch_bounds__(512) void gat_gemm(
    const float* __restrict__ x,    // [B,C,N]
    const float* __restrict__ W,    // [C,C] row-major W[o][c]
    const float* __restrict__ a,    // [2C]
    uint32* __restrict__ wht,       // [B,N,C/2] packed bf16 pairs
    float* __restrict__ si,         // [B,N]
    float* __restrict__ sj) {       // [B,N]
  __shared__ float xs[CC][TNG];       // 32 KB  xs[c][n]
  __shared__ float red[2][8][TNG];    // 4 KB   si/sj partials

  const int b    = blockIdx.y;
  const int n0   = blockIdx.x * TNG;
  const int t    = threadIdx.x;
  const int lane = t & 63;
  const int wv   = t >> 6;            // 8 waves; wave owns channels wv*16..+15

  // Stage x tile: consecutive lanes -> consecutive nodes (coalesced).
  const float* xb = x + (size_t)b * CC * NN;
#pragma unroll
  for (int i = 0; i < 16; ++i) {
    int e = t + i * 512;
    int c = e >> 6, n = e & 63;
    int gn = n0 + n;
    xs[c][n] = (gn < NN) ? xb[c * NN + gn] : 0.f;
  }
  __syncthreads();

  // Wave-uniform channel base -> scalar W pointer -> s_load_dwordx4.
  const int co = __builtin_amdgcn_readfirstlane(wv << 4);
  const float4* Wv = (const float4*)(W + co * CC);   // 16 rows x 32 float4

  float acc[16];
#pragma unroll
  for (int j = 0; j < 16; ++j) acc[j] = 0.f;

  for (int c0 = 0; c0 < CC; c0 += 8) {               // uniform loop counter
    float xv[8];
#pragma unroll
    for (int u = 0; u < 8; ++u) xv[u] = xs[c0 + u][lane];  // 2-way bank = free
    const int q = c0 >> 2;
#pragma unroll
    for (int j = 0; j < 16; ++j) {
      float4 w0 = Wv[j * 32 + q];      // scalar loads (uniform addr)
      float4 w1 = Wv[j * 32 + q + 1];
      acc[j] = fmaf(w0.x, xv[0], acc[j]);
      acc[j] = fmaf(w0.y, xv[1], acc[j]);
      acc[j] = fmaf(w0.z, xv[2], acc[j]);
      acc[j] = fmaf(w0.w, xv[3], acc[j]);
      acc[j] = fmaf(w1.x, xv[4], acc[j]);
      acc[j] = fmaf(w1.y, xv[5], acc[j]);
      acc[j] = fmaf(w1.z, xv[6], acc[j]);
      acc[j] = fmaf(w1.w, xv[7], acc[j]);
    }
  }

  // si/sj partials over this wave's 16 channels (a[] is uniform -> s_load).
  const float* ai = a + co;
  const float* aj = a + CC + co;
  float psi = 0.f, psj = 0.f;
#pragma unroll
  for (int j = 0; j < 16; ++j) {
    psi = fmaf(ai[j], acc[j], psi);
    psj = fmaf(aj[j], acc[j], psj);
  }
  red[0][wv][lane] = psi;
  red[1][wv][lane] = psj;

  // Store bf16-packed wht row segment (32 B/thread, uint4-aligned since co%16==0).
  const int gn = n0 + lane;
  if (gn < NN) {
    uint32 pk[8];
#pragma unroll
    for (int j = 0; j < 8; ++j) pk[j] = bf16pair(acc[2 * j], acc[2 * j + 1]);
    uint4* wb = (uint4*)(wht + ((size_t)(b * NN + gn)) * (CC / 2) + (co >> 1));
    wb[0] = make_uint4(pk[0], pk[1], pk[2], pk[3]);
    wb[1] = make_uint4(pk[4], pk[5], pk[6], pk[7]);
  }

  __syncthreads();
  if (t < TNG) {
    int g = n0 + t;
    if (g < NN) {
      float s1 = 0.f, s2 = 0.f;
#pragma unroll
      for (int w = 0; w < 8; ++w) { s1 += red[0][w][t]; s2 += red[1][w][t]; }
      si[b * NN + g] = s1;
      sj[b * NN + g] = s2;
    }
  }
}

// ---------------- Gather: bf16 rows (256 B), L2-resident ----------------
__global__ __launch_bounds__(256) void gat_gather(
    const int* __restrict__ ei,      // [2,B,N,K]
    const uint32* __restrict__ wht,  // [B,N,C/2] bf16 pairs
    const float* __restrict__ si,    // [B,N]
    const float* __restrict__ sj,    // [B,N]
    float* __restrict__ out) {       // [B,C,N]
  __shared__ float Am[TNA][KK];        // 1 KB
  __shared__ int   jd[TNA][KK];        // 1 KB
  __shared__ float outT[CC][TNA + 1];  // 8.5 KB

  const int b  = blockIdx.y;
  const int n0 = blockIdx.x * TNA;
  const int t  = threadIdx.x;

  const int* eij = ei + b * NN * KK;          // edge_index[0][b] -> j (source)
  const int* eii = ei + (BB + b) * NN * KK;   // edge_index[1][b] -> i (dest)
  const float* sib = si + b * NN;
  const float* sjb = sj + b * NN;

  // Phase A: one edge per thread (256 = TNA*KK).
  {
    int nn = t >> 4, k = t & 15, gn = n0 + nn;
    float el = 0.f; int jj = 0;
    if (gn < NN) {
      jj = eij[gn * KK + k];
      int ii = eii[gn * KK + k];
      float v = sib[ii] + sjb[jj];
      el = (v > 0.f) ? v : 0.2f * v;   // leaky_relu(0.2)
    }
    Am[nn][k] = el;
    jd[nn][k] = jj;
  }
  __syncthreads();

  // Phase B: softmax over K=16 per node.
  if (t < TNA) {
    float mx = Am[t][0];
#pragma unroll
    for (int k = 1; k < KK; ++k) mx = fmaxf(mx, Am[t][k]);
    float s = 0.f, ex[KK];
#pragma unroll
    for (int k = 0; k < KK; ++k) { ex[k] = __expf(Am[t][k] - mx); s += ex[k]; }
    float inv = 1.f / s;
#pragma unroll
    for (int k = 0; k < KK; ++k) Am[t][k] = ex[k] * inv;
  }
  __syncthreads();

  // Phase C: wave = one node row (64 lanes x 1 uint = 256 B); 16 independent
  // gathers in flight per node.
  const int cp = t & 63;      // channel pair
  const int nw = t >> 6;
  const uint32* whtb = wht + (size_t)b * NN * (CC / 2);
  for (int nn = nw; nn < TNA; nn += 4) {
    int gn = n0 + nn;
    float ax = 0.f, ay = 0.f;
    if (gn < NN) {
      int idx[KK]; float wk[KK];
#pragma unroll
      for (int k = 0; k < KK; ++k) { idx[k] = jd[nn][k]; wk[k] = Am[nn][k]; }
      uint32 v[KK];
#pragma unroll
      for (int k = 0; k < KK; ++k)
        v[k] = whtb[(size_t)idx[k] * (CC / 2) + cp];
#pragma unroll
      for (int k = 0; k < KK; ++k) {
        ax = fmaf(wk[k], __uint_as_float(v[k] << 16), ax);
        ay = fmaf(wk[k], __uint_as_float(v[k] & 0xffff0000u), ay);
      }
    }
    outT[2 * cp][nn]     = ax;
    outT[2 * cp + 1][nn] = ay;
  }
  __syncthreads();

  // Phase D: coalesced channel-major store.
  float* outb = out + (size_t)b * CC * NN;
#pragma unroll
  for (int i = 0; i < (CC * TNA) / 256; ++i) {   // 8 iters
    int e = t + i * 256;
    int c = e >> 4, nn = e & 15;
    int gn = n0 + nn;
    if (gn < NN) outb[c * NN + gn] = outT[c][nn];
  }
}

extern "C" void kernel_launch(void* const* d_in, const int* in_sizes, int n_in,
                              void* d_out, int out_size, void* d_ws, size_t ws_size,
                              hipStream_t stream) {
  const float* x  = (const float*)d_in[0];   // [B,C,N,1]
  const int*   ei = (const int*)d_in[1];     // [2,B,N,K]
  const float* W  = (const float*)d_in[2];   // [C,C]
  const float* a  = (const float*)d_in[3];   // [2C]
  float* out = (float*)d_out;                // [B,C,N,1]

  uint32* wht = (uint32*)d_ws;               // [B*N*C/2] bf16 pairs (5.1 MB)
  float*  si  = (float*)(wht + (size_t)BB * NN * (CC / 2));
  float*  sj  = si + BB * NN;

  dim3 g1((NN + TNG - 1) / TNG, BB);   // 157 x 2, 512 threads
  dim3 g2((NN + TNA - 1) / TNA, BB);   // 625 x 2, 256 threads
  gat_gemm<<<g1, 512, 0, stream>>>(x, W, a, wht, si, sj);
  gat_gather<<<g2, 256, 0, stream>>>(ei, wht, si, sj, out);
}

// Round 4
// 88.190 us; speedup vs baseline: 1.5981x; 1.1982x over previous
//
#include <hip/hip_runtime.h>

// GAT-style graph conv: B=2, C=128, N=10000, K=16, fp32 in/out.
//   k1 (gemm, MFMA bf16): wht[b][n][c] = sum_c' W[c][c']*x[b][c'][n] (bf16 packed)
//               si[b][n] = a[0:C].wh[n], sj[b][n] = a[C:2C].wh[n]  (fp32, from acc)
//   k2 (gather): e = leaky(si[idx_i]+sj[idx_j]); A = softmax_k(e)
//               out[b][c][n] = sum_k A[n,k] * wht[b][idx_j[n,k]][c]

#define BB 2
#define CC 128
#define NN 10000
#define KK 16
#define TNG 64    // nodes per gemm block
#define TNA 16    // nodes per gather block
#define LSTR 136  // LDS row stride in ushorts: rows 16B-aligned (136*2=272=17*16)

typedef unsigned int uint32;
typedef unsigned short ushort16_t;
typedef __attribute__((ext_vector_type(8))) short short8;   // bf16 A/B frag (4 VGPR)
typedef __attribute__((ext_vector_type(4))) float floatx4;  // f32 C/D frag

__device__ __forceinline__ uint32 bf16pair(float lo, float hi) {
  // round-to-nearest-even bf16, packed (lo low 16, hi high 16)
  uint32 ulo = __float_as_uint(lo);
  uint32 uhi = __float_as_uint(hi);
  ulo += 0x7fffu + ((ulo >> 16) & 1u);
  uhi += 0x7fffu + ((uhi >> 16) & 1u);
  return (ulo >> 16) | (uhi & 0xffff0000u);
}

// ---------------- GEMM via MFMA 16x16x32 bf16 ----------------
// Block: 256 thr (4 waves). Wave w: channels w*32..w*32+31 x all 64 nodes.
// Tiles: ci in {0,1} (16-ch), nj in {0..3} (16-node); 4 k-steps of 32.
__global__ __launch_bounds__(256) void gat_gemm(
    const float* __restrict__ x,    // [B,C,N]
    const float* __restrict__ W,    // [C,C] row-major W[o][c]
    const float* __restrict__ a,    // [2C]
    uint32* __restrict__ wht,       // [B,N,C/2] bf16 pairs
    float* __restrict__ si,         // [B,N]
    float* __restrict__ sj) {       // [B,N]
  __shared__ ushort16_t Wl[CC * LSTR];    // 34816 B  W as bf16, row-major, padded
  __shared__ ushort16_t xs[TNG * LSTR];   // 17408 B  x tile, node-major [n][k]
  __shared__ float red[2][4][4][16];      // 2048 B   [si/sj][wave][nj][col]

  const int b  = blockIdx.y;
  const int n0 = blockIdx.x * TNG;
  const int t  = threadIdx.x;

  // --- Stage W -> bf16 LDS (coalesced float2 reads, 2-way-free LDS writes) ---
  {
    const float2* Wg = (const float2*)W;         // 8192 float2
    uint32* Wd = (uint32*)Wl;                    // dword view, row stride 68
#pragma unroll
    for (int i = 0; i < 32; ++i) {
      int f2 = t + i * 256;
      float2 v = Wg[f2];
      int o = f2 >> 6, c2 = f2 & 63;
      Wd[o * 68 + c2] = bf16pair(v.x, v.y);
    }
  }
  // --- Stage x tile, transpose to node-major bf16 ---
  {
    const float* xb = x + (size_t)b * CC * NN;
    uint32* xd = (uint32*)xs;
#pragma unroll
    for (int i = 0; i < 16; ++i) {
      int e = t + i * 256;
      int n = e & 63, cp = e >> 6;     // cp = channel pair 0..63
      int c = cp * 2, gn = n0 + n;
      float v0 = 0.f, v1 = 0.f;
      if (gn < NN) { v0 = xb[c * NN + gn]; v1 = xb[(c + 1) * NN + gn]; }
      xd[n * 68 + cp] = bf16pair(v0, v1);
    }
  }
  __syncthreads();

  const int w    = t >> 6;       // wave 0..3 -> channel group w*32
  const int lane = t & 63;
  const int col  = lane & 15;    // MFMA col (node) / A row (channel)
  const int q    = lane >> 4;    // quad

  floatx4 acc[2][4];
#pragma unroll
  for (int ci = 0; ci < 2; ++ci)
#pragma unroll
    for (int nj = 0; nj < 4; ++nj) acc[ci][nj] = (floatx4){0.f, 0.f, 0.f, 0.f};

#pragma unroll
  for (int s = 0; s < 4; ++s) {            // k-step: k0 = s*32
    const int ko = s * 32 + q * 8;
    short8 af[2], bf[4];
#pragma unroll
    for (int ci = 0; ci < 2; ++ci)
      af[ci] = *(const short8*)(Wl + (w * 32 + ci * 16 + col) * LSTR + ko);
#pragma unroll
    for (int nj = 0; nj < 4; ++nj)
      bf[nj] = *(const short8*)(xs + (nj * 16 + col) * LSTR + ko);
#pragma unroll
    for (int ci = 0; ci < 2; ++ci)
#pragma unroll
      for (int nj = 0; nj < 4; ++nj)
        acc[ci][nj] = __builtin_amdgcn_mfma_f32_16x16x32_bf16(af[ci], bf[nj], acc[ci][nj], 0, 0, 0);
  }

  // --- Epilogue: wht bf16 stores + si/sj partials ---
  // D layout: channel = w*32 + ci*16 + q*4 + r, node = n0 + nj*16 + col.
  float ar[2][4], aj4[2][4];
#pragma unroll
  for (int ci = 0; ci < 2; ++ci)
#pragma unroll
    for (int r = 0; r < 4; ++r) {
      int ch = w * 32 + ci * 16 + q * 4 + r;
      ar[ci][r]  = a[ch];
      aj4[ci][r] = a[CC + ch];
    }

#pragma unroll
  for (int nj = 0; nj < 4; ++nj) {
    int node = n0 + nj * 16 + col;
    float psi = 0.f, psj = 0.f;
#pragma unroll
    for (int ci = 0; ci < 2; ++ci) {
#pragma unroll
      for (int r = 0; r < 4; ++r) {
        psi = fmaf(ar[ci][r], acc[ci][nj][r], psi);
        psj = fmaf(aj4[ci][r], acc[ci][nj][r], psj);
      }
      if (node < NN) {
        uint2 pk;
        pk.x = bf16pair(acc[ci][nj][0], acc[ci][nj][1]);
        pk.y = bf16pair(acc[ci][nj][2], acc[ci][nj][3]);
        uint2* dst = (uint2*)(wht + ((size_t)(b * NN + node)) * (CC / 2) + w * 16 + ci * 8 + q * 2);
        *dst = pk;
      }
    }
    // reduce over quads: lanes l, l+16, l+32, l+48 share node col
    psi += __shfl_down(psi, 32);
    psi += __shfl_down(psi, 16);
    psj += __shfl_down(psj, 32);
    psj += __shfl_down(psj, 16);
    if (q == 0) { red[0][w][nj][col] = psi; red[1][w][nj][col] = psj; }
  }
  __syncthreads();

  if (t < TNG) {
    int gn = n0 + t;
    if (gn < NN) {
      int nj = t >> 4, cl = t & 15;
      float s1 = 0.f, s2 = 0.f;
#pragma unroll
      for (int ww = 0; ww < 4; ++ww) { s1 += red[0][ww][nj][cl]; s2 += red[1][ww][nj][cl]; }
      si[b * NN + gn] = s1;
      sj[b * NN + gn] = s2;
    }
  }
}

// ---------------- Gather: bf16 rows (256 B), 32 gathers in flight ----------------
__global__ __launch_bounds__(256) void gat_gather(
    const int* __restrict__ ei,      // [2,B,N,K]
    const uint32* __restrict__ wht,  // [B,N,C/2] bf16 pairs
    const float* __restrict__ si,    // [B,N]
    const float* __restrict__ sj,    // [B,N]
    float* __restrict__ out) {       // [B,C,N]
  __shared__ float Am[TNA][KK];        // 1 KB
  __shared__ int   jd[TNA][KK];        // 1 KB
  __shared__ float outT[CC][TNA + 1];  // 8.5 KB

  const int b  = blockIdx.y;
  const int n0 = blockIdx.x * TNA;
  const int t  = threadIdx.x;

  const int* eij = ei + b * NN * KK;          // edge_index[0][b] -> j (source)
  const int* eii = ei + (BB + b) * NN * KK;   // edge_index[1][b] -> i (dest)
  const float* sib = si + b * NN;
  const float* sjb = sj + b * NN;

  // Phase A: one edge per thread.
  {
    int nn = t >> 4, k = t & 15, gn = n0 + nn;
    float el = 0.f; int jj = 0;
    if (gn < NN) {
      jj = eij[gn * KK + k];
      int ii = eii[gn * KK + k];
      float v = sib[ii] + sjb[jj];
      el = (v > 0.f) ? v : 0.2f * v;   // leaky_relu(0.2)
    }
    Am[nn][k] = el;
    jd[nn][k] = jj;
  }
  __syncthreads();

  // Phase B: softmax over K=16 per node.
  if (t < TNA) {
    float mx = Am[t][0];
#pragma unroll
    for (int k = 1; k < KK; ++k) mx = fmaxf(mx, Am[t][k]);
    float s = 0.f, ex[KK];
#pragma unroll
    for (int k = 0; k < KK; ++k) { ex[k] = __expf(Am[t][k] - mx); s += ex[k]; }
    float inv = 1.f / s;
#pragma unroll
    for (int k = 0; k < KK; ++k) Am[t][k] = ex[k] * inv;
  }
  __syncthreads();

  // Phase C: wave = one node row (64 lanes x 1 dword = 256 B).
  // Two nodes processed together -> 32 independent gathers in flight.
  const int cp = t & 63;
  const int nw = t >> 6;
  const uint32* whtb = wht + (size_t)b * NN * (CC / 2);
#pragma unroll
  for (int half = 0; half < 2; ++half) {
    int na = nw + half * 4;        // nodes na and na+8
    int idx[2][KK]; float wk[2][KK];
#pragma unroll
    for (int p = 0; p < 2; ++p) {
      int nn = na + p * 8;
      const uint4*   jp = (const uint4*)&jd[nn][0];   // broadcast b128 reads
      const float4*  ap = (const float4*)&Am[nn][0];
#pragma unroll
      for (int g = 0; g < 4; ++g) {
        uint4  jv = jp[g];
        float4 av = ap[g];
        idx[p][4 * g + 0] = jv.x; idx[p][4 * g + 1] = jv.y;
        idx[p][4 * g + 2] = jv.z; idx[p][4 * g + 3] = jv.w;
        wk[p][4 * g + 0] = av.x;  wk[p][4 * g + 1] = av.y;
        wk[p][4 * g + 2] = av.z;  wk[p][4 * g + 3] = av.w;
      }
    }
    uint32 v[2][KK];
#pragma unroll
    for (int p = 0; p < 2; ++p)
#pragma unroll
      for (int k = 0; k < KK; ++k)
        v[p][k] = whtb[(size_t)idx[p][k] * (CC / 2) + cp];
#pragma unroll
    for (int p = 0; p < 2; ++p) {
      int nn = na + p * 8;
      float ax = 0.f, ay = 0.f;
#pragma unroll
      for (int k = 0; k < KK; ++k) {
        ax = fmaf(wk[p][k], __uint_as_float(v[p][k] << 16), ax);
        ay = fmaf(wk[p][k], __uint_as_float(v[p][k] & 0xffff0000u), ay);
      }
      outT[2 * cp][nn]     = ax;
      outT[2 * cp + 1][nn] = ay;
    }
  }
  __syncthreads();

  // Phase D: coalesced channel-major store.
  float* outb = out + (size_t)b * CC * NN;
#pragma unroll
  for (int i = 0; i < (CC * TNA) / 256; ++i) {   // 8 iters
    int e = t + i * 256;
    int c = e >> 4, nn = e & 15;
    int gn = n0 + nn;
    if (gn < NN) outb[c * NN + gn] = outT[c][nn];
  }
}

extern "C" void kernel_launch(void* const* d_in, const int* in_sizes, int n_in,
                              void* d_out, int out_size, void* d_ws, size_t ws_size,
                              hipStream_t stream) {
  const float* x  = (const float*)d_in[0];   // [B,C,N,1]
  const int*   ei = (const int*)d_in[1];     // [2,B,N,K]
  const float* W  = (const float*)d_in[2];   // [C,C]
  const float* a  = (const float*)d_in[3];   // [2C]
  float* out = (float*)d_out;                // [B,C,N,1]

  uint32* wht = (uint32*)d_ws;               // [B*N*C/2] bf16 pairs (5.12 MB)
  float*  si  = (float*)(wht + (size_t)BB * NN * (CC / 2));
  float*  sj  = si + BB * NN;

  dim3 g1((NN + TNG - 1) / TNG, BB);   // 157 x 2, 256 threads
  dim3 g2((NN + TNA - 1) / TNA, BB);   // 625 x 2, 256 threads
  gat_gemm<<<g1, 256, 0, stream>>>(x, W, a, wht, si, sj);
  gat_gather<<<g2, 256, 0, stream>>>(ei, wht, si, sj, out);
}

// Round 5
// 87.349 us; speedup vs baseline: 1.6135x; 1.0096x over previous
//
#include <hip/hip_runtime.h>

// GAT-style graph conv: B=2, C=128, N=10000, K=16, fp32 in/out.
//   k1 (gemm, MFMA bf16): wht[b][n][c] = sum_c' W[c][c']*x[b][c'][n] (bf16 packed)
//               si[b][n] = a[0:C].wh[n], sj[b][n] = a[C:2C].wh[n]  (fp32, from acc)
//   k2 (gather): e = leaky(si[idx_i]+sj[idx_j]); A = softmax_k(e)
//               out[b][c][n] = sum_k A[n,k] * wht[b][idx_j[n,k]][c]
// Gather is XCD-pinned: batch = (blockIdx%8)>>2 so each XCD's L2 (4 MiB) only
// caches its batch's 2.56 MB of wht -> random row-gathers become L2 hits.

#define BB 2
#define CC 128
#define NN 10000
#define KK 16
#define TNG 32    // nodes per gemm block
#define TNA 16    // nodes per gather block
#define LSTR 136  // xs row stride in ushorts (272 B = 17*16 -> b128-aligned rows)

typedef unsigned int uint32;
typedef __attribute__((ext_vector_type(8))) short short8;   // bf16 A/B frag
typedef __attribute__((ext_vector_type(4))) float floatx4;  // f32 C/D frag

__device__ __forceinline__ uint32 bf16pair(float lo, float hi) {
  // round-to-nearest-even bf16, packed (lo low 16, hi high 16)
  uint32 ulo = __float_as_uint(lo);
  uint32 uhi = __float_as_uint(hi);
  ulo += 0x7fffu + ((ulo >> 16) & 1u);
  uhi += 0x7fffu + ((uhi >> 16) & 1u);
  return (ulo >> 16) | (uhi & 0xffff0000u);
}

// ---------------- GEMM via MFMA 16x16x32 bf16, register-resident W frags ----
// Block: 256 thr (4 waves). Wave w: channels w*32..+31 x 32 nodes.
__global__ __launch_bounds__(256) void gat_gemm(
    const float* __restrict__ x,    // [B,C,N]
    const float* __restrict__ W,    // [C,C] row-major W[o][c]
    const float* __restrict__ a,    // [2C]
    uint32* __restrict__ wht,       // [B,N,C/2] bf16 pairs
    float* __restrict__ si,         // [B,N]
    float* __restrict__ sj) {       // [B,N]
  __shared__ unsigned short xs[TNG * LSTR];   // 8704 B, node-major bf16 x tile
  __shared__ float red[2][4][2][16];          // 1 KB si/sj partials

  const int b    = blockIdx.y;
  const int n0   = blockIdx.x * TNG;
  const int t    = threadIdx.x;
  const int w    = t >> 6;       // wave -> channel group w*32
  const int lane = t & 63;
  const int col  = lane & 15;    // MFMA col (node) / A row (channel)
  const int q    = lane >> 4;    // quad -> k offset q*8

  // --- Stage x tile, transpose to node-major bf16 (coalesced 128B row reads) ---
  {
    const float* xb = x + (size_t)b * CC * NN;
    uint32* xd = (uint32*)xs;
#pragma unroll
    for (int i = 0; i < 8; ++i) {
      int e = t + i * 256;
      int n = e & 31, cp = e >> 5;     // cp = channel pair 0..63
      int c = cp * 2, gn = n0 + n;
      float v0 = 0.f, v1 = 0.f;
      if (gn < NN) { v0 = xb[c * NN + gn]; v1 = xb[(c + 1) * NN + gn]; }
      xd[n * 68 + cp] = bf16pair(v0, v1);
    }
  }

  // --- A-fragments straight from global fp32 W -> bf16 registers (no LDS) ---
  short8 af[2][4];
#pragma unroll
  for (int ci = 0; ci < 2; ++ci) {
    const float* wr = W + (w * 32 + ci * 16 + col) * CC;
#pragma unroll
    for (int s = 0; s < 4; ++s) {
      float4 f0 = *(const float4*)(wr + s * 32 + q * 8);
      float4 f1 = *(const float4*)(wr + s * 32 + q * 8 + 4);
      union { uint32 u[4]; short8 v; } cv;
      cv.u[0] = bf16pair(f0.x, f0.y);
      cv.u[1] = bf16pair(f0.z, f0.w);
      cv.u[2] = bf16pair(f1.x, f1.y);
      cv.u[3] = bf16pair(f1.z, f1.w);
      af[ci][s] = cv.v;
    }
  }
  __syncthreads();

  floatx4 acc[2][2];
#pragma unroll
  for (int ci = 0; ci < 2; ++ci)
#pragma unroll
    for (int nj = 0; nj < 2; ++nj) acc[ci][nj] = (floatx4){0.f, 0.f, 0.f, 0.f};

#pragma unroll
  for (int s = 0; s < 4; ++s) {
    short8 bf[2];
#pragma unroll
    for (int nj = 0; nj < 2; ++nj)
      bf[nj] = *(const short8*)(xs + (nj * 16 + col) * LSTR + s * 32 + q * 8);
#pragma unroll
    for (int ci = 0; ci < 2; ++ci)
#pragma unroll
      for (int nj = 0; nj < 2; ++nj)
        acc[ci][nj] = __builtin_amdgcn_mfma_f32_16x16x32_bf16(af[ci][s], bf[nj], acc[ci][nj], 0, 0, 0);
  }

  // --- Epilogue: channel = w*32+ci*16+q*4+r, node = n0+nj*16+col ---
  float ar[2][4], aj4[2][4];
#pragma unroll
  for (int ci = 0; ci < 2; ++ci)
#pragma unroll
    for (int r = 0; r < 4; ++r) {
      int ch = w * 32 + ci * 16 + q * 4 + r;
      ar[ci][r]  = a[ch];
      aj4[ci][r] = a[CC + ch];
    }

#pragma unroll
  for (int nj = 0; nj < 2; ++nj) {
    int node = n0 + nj * 16 + col;
    float psi = 0.f, psj = 0.f;
#pragma unroll
    for (int ci = 0; ci < 2; ++ci) {
#pragma unroll
      for (int r = 0; r < 4; ++r) {
        psi = fmaf(ar[ci][r], acc[ci][nj][r], psi);
        psj = fmaf(aj4[ci][r], acc[ci][nj][r], psj);
      }
      if (node < NN) {
        uint2 pk;
        pk.x = bf16pair(acc[ci][nj][0], acc[ci][nj][1]);
        pk.y = bf16pair(acc[ci][nj][2], acc[ci][nj][3]);
        uint2* dst = (uint2*)(wht + ((size_t)(b * NN + node)) * (CC / 2) + w * 16 + ci * 8 + q * 2);
        *dst = pk;
      }
    }
    psi += __shfl_down(psi, 32);
    psi += __shfl_down(psi, 16);
    psj += __shfl_down(psj, 32);
    psj += __shfl_down(psj, 16);
    if (q == 0) { red[0][w][nj][col] = psi; red[1][w][nj][col] = psj; }
  }
  __syncthreads();

  if (t < TNG) {
    int gn = n0 + t;
    if (gn < NN) {
      int nj = t >> 4, cl = t & 15;
      float s1 = 0.f, s2 = 0.f;
#pragma unroll
      for (int ww = 0; ww < 4; ++ww) { s1 += red[0][ww][nj][cl]; s2 += red[1][ww][nj][cl]; }
      si[b * NN + gn] = s1;
      sj[b * NN + gn] = s2;
    }
  }
}

// ---------------- Gather: XCD-pinned, bf16 rows, 32 gathers in flight -------
__global__ __launch_bounds__(256) void gat_gather(
    const int* __restrict__ ei,      // [2,B,N,K]
    const uint32* __restrict__ wht,  // [B,N,C/2] bf16 pairs
    const float* __restrict__ si,    // [B,N]
    const float* __restrict__ sj,    // [B,N]
    float* __restrict__ out) {       // [B,C,N]
  __shared__ float Am[TNA][KK];        // 1 KB
  __shared__ int   jd[TNA][KK];        // 1 KB
  __shared__ float outT[CC][TNA + 1];  // 8.5 KB

  // XCD pinning: xcd = bk%8; XCDs 0-3 -> batch 0, 4-7 -> batch 1.
  const int bk   = blockIdx.x;
  const int xcd  = bk & 7;
  const int b    = xcd >> 2;
  const int slot = (bk >> 3) * 4 + (xcd & 3);
  if (slot >= (NN + TNA - 1) / TNA) return;   // uniform early-out (625 slots/batch)
  const int n0 = slot * TNA;
  const int t  = threadIdx.x;

  const int* eij = ei + b * NN * KK;          // edge_index[0][b] -> j (source)
  const int* eii = ei + (BB + b) * NN * KK;   // edge_index[1][b] -> i (dest)
  const float* sib = si + b * NN;
  const float* sjb = sj + b * NN;

  // Phase A: one edge per thread.
  {
    int nn = t >> 4, k = t & 15, gn = n0 + nn;
    float el = 0.f; int jj = 0;
    if (gn < NN) {
      jj = eij[gn * KK + k];
      int ii = eii[gn * KK + k];
      float v = sib[ii] + sjb[jj];
      el = (v > 0.f) ? v : 0.2f * v;   // leaky_relu(0.2)
    }
    Am[nn][k] = el;
    jd[nn][k] = jj;
  }
  __syncthreads();

  // Phase B: softmax over K=16 per node.
  if (t < TNA) {
    float mx = Am[t][0];
#pragma unroll
    for (int k = 1; k < KK; ++k) mx = fmaxf(mx, Am[t][k]);
    float s = 0.f, ex[KK];
#pragma unroll
    for (int k = 0; k < KK; ++k) { ex[k] = __expf(Am[t][k] - mx); s += ex[k]; }
    float inv = 1.f / s;
#pragma unroll
    for (int k = 0; k < KK; ++k) Am[t][k] = ex[k] * inv;
  }
  __syncthreads();

  // Phase C: wave = one node row (64 lanes x 1 dword = 256 B); two nodes
  // batched -> 32 independent gathers in flight (all L2-local to this XCD).
  const int cp = t & 63;
  const int nw = t >> 6;
  const uint32* whtb = wht + (size_t)b * NN * (CC / 2);
#pragma unroll
  for (int half = 0; half < 2; ++half) {
    int na = nw + half * 4;        // nodes na and na+8
    int idx[2][KK]; float wk[2][KK];
#pragma unroll
    for (int p = 0; p < 2; ++p) {
      int nn = na + p * 8;
      const uint4*  jp = (const uint4*)&jd[nn][0];   // broadcast b128 reads
      const float4* ap = (const float4*)&Am[nn][0];
#pragma unroll
      for (int g = 0; g < 4; ++g) {
        uint4  jv = jp[g];
        float4 av = ap[g];
        idx[p][4 * g + 0] = jv.x; idx[p][4 * g + 1] = jv.y;
        idx[p][4 * g + 2] = jv.z; idx[p][4 * g + 3] = jv.w;
        wk[p][4 * g + 0] = av.x;  wk[p][4 * g + 1] = av.y;
        wk[p][4 * g + 2] = av.z;  wk[p][4 * g + 3] = av.w;
      }
    }
    uint32 v[2][KK];
#pragma unroll
    for (int p = 0; p < 2; ++p)
#pragma unroll
      for (int k = 0; k < KK; ++k)
        v[p][k] = whtb[(size_t)idx[p][k] * (CC / 2) + cp];
#pragma unroll
    for (int p = 0; p < 2; ++p) {
      int nn = na + p * 8;
      float ax = 0.f, ay = 0.f;
#pragma unroll
      for (int k = 0; k < KK; ++k) {
        ax = fmaf(wk[p][k], __uint_as_float(v[p][k] << 16), ax);
        ay = fmaf(wk[p][k], __uint_as_float(v[p][k] & 0xffff0000u), ay);
      }
      outT[2 * cp][nn]     = ax;
      outT[2 * cp + 1][nn] = ay;
    }
  }
  __syncthreads();

  // Phase D: coalesced channel-major store.
  float* outb = out + (size_t)b * CC * NN;
#pragma unroll
  for (int i = 0; i < (CC * TNA) / 256; ++i) {   // 8 iters
    int e = t + i * 256;
    int c = e >> 4, nn = e & 15;
    int gn = n0 + nn;
    if (gn < NN) outb[c * NN + gn] = outT[c][nn];
  }
}

extern "C" void kernel_launch(void* const* d_in, const int* in_sizes, int n_in,
                              void* d_out, int out_size, void* d_ws, size_t ws_size,
                              hipStream_t stream) {
  const float* x  = (const float*)d_in[0];   // [B,C,N,1]
  const int*   ei = (const int*)d_in[1];     // [2,B,N,K]
  const float* W  = (const float*)d_in[2];   // [C,C]
  const float* a  = (const float*)d_in[3];   // [2C]
  float* out = (float*)d_out;                // [B,C,N,1]

  uint32* wht = (uint32*)d_ws;               // [B*N*C/2] bf16 pairs (5.12 MB)
  float*  si  = (float*)(wht + (size_t)BB * NN * (CC / 2));
  float*  sj  = si + BB * NN;

  dim3 g1((NN + TNG - 1) / TNG, BB);   // 313 x 2, 256 threads
  gat_gemm<<<g1, 256, 0, stream>>>(x, W, a, wht, si, sj);
  // 157 blocks per XCD-slot group * 8 = covers 628 slots/batch (625 used)
  gat_gather<<<dim3(157 * 8), 256, 0, stream>>>(ei, wht, si, sj, out);
}